// Round 14
// baseline (141.068 us; speedup 1.0000x reference)
//
#include <hip/hip_runtime.h>
#include <hip/hip_bf16.h>

typedef __attribute__((ext_vector_type(8)))  short short8;
typedef __attribute__((ext_vector_type(16))) float f32x16;

#define B_SZ 32
#define T_SZ 4096
#define H_SZ 512
#define NROWS (B_SZ * T_SZ)   // 131072

// packed fp32x2 -> bf16x2 (RNE)
static __device__ __forceinline__ unsigned int pack2(float a, float b) {
  unsigned int r;
  asm("v_cvt_pk_bf16_f32 %0, %1, %2" : "=v"(r) : "v"(a), "v"(b));
  return r;
}
// branch-free tanh, exact saturation: 1 - 2/(e^{2x}+1)
static __device__ __forceinline__ float fast_tanh(float x) {
  float e = __expf(2.0f * x);
  return 1.0f - 2.0f / (e + 1.0f);
}

// ---- W fp32 (512x512) -> bf16 fragments for mfma_32x32x16, chunk-major ----
// uint4 s = c*4096 + j*2048 + kt*64 + lane
// holds W[g = c*64 + j*32 + (lane&31)][kt*16 + (lane>>5)*8 .. +8]
// one chunk c = 64 g x 512 k = 64 KB contiguous, fragment-linear.
__global__ __launch_bounds__(256) void prep_w_kernel(
    const float* __restrict__ W, uint4* __restrict__ Wfrag) {
  int s = blockIdx.x * 256 + threadIdx.x;   // 0..32767
  int lane = s & 63;
  int kt   = (s >> 6) & 31;
  int j    = (s >> 11) & 1;
  int c    = s >> 12;
  int g  = c * 64 + j * 32 + (lane & 31);
  int k0 = kt * 16 + (lane >> 5) * 8;
  const float4* Wf4 = reinterpret_cast<const float4*>(W);
  float4 lo = Wf4[g * 128 + (k0 >> 2)];
  float4 hi = Wf4[g * 128 + (k0 >> 2) + 1];
  uint4 u;
  u.x = pack2(lo.x, lo.y); u.y = pack2(lo.z, lo.w);
  u.z = pack2(hi.x, hi.y); u.w = pack2(hi.z, hi.w);
  Wfrag[s] = u;
}

// ---- fused: scores (32x32x16 MFMA, big bursts) + softmax + numerator ----
// 256 thr = 4 waves, wave owns 32 rows (A full-K in regs: 32 frags = 128 VGPR).
// W: 8 chunks of 64 g x 512 k (64 KB LDS, single-buffered). Per chunk each
// wave: 64 ds_read_b128 + 64 mfma_32x32x16 between one barrier pair.
__global__ __launch_bounds__(256, 2) void score_fused_kernel(
    const float* __restrict__ X, const uint4* __restrict__ Wfrag,
    const float* __restrict__ v,
    float* __restrict__ num, float2* __restrict__ md) {
  __shared__ unsigned char WsB[65536];   // [j(2)][kt(32)][lane(64)][16B]
  __shared__ float sLDS[128];
  __shared__ float pLDS[128];
  __shared__ float mred[2], dred[2];

  const int tid   = threadIdx.x;
  const int lane  = tid & 63;
  const int wave  = tid >> 6;
  const int l31   = lane & 31;
  const int half  = lane >> 5;
  const size_t rowbase = (size_t)blockIdx.x * 128;

  // A fragments: lane holds X[rowbase + wave*32 + l31][kt*16 + half*8 .. +8]
  short8 afrag[32];
  {
    const float4* xr = reinterpret_cast<const float4*>(
        X + (rowbase + wave * 32 + l31) * H_SZ);
    #pragma unroll
    for (int kt = 0; kt < 32; ++kt) {
      float4 lo = xr[kt * 4 + half * 2];
      float4 hi = xr[kt * 4 + half * 2 + 1];
      union { uint4 u; short8 s; } cv;
      cv.u.x = pack2(lo.x, lo.y); cv.u.y = pack2(lo.z, lo.w);
      cv.u.z = pack2(hi.x, hi.y); cv.u.w = pack2(hi.z, hi.w);
      afrag[kt] = cv.s;
    }
  }

  // per-lane score partials: red[r] for the 16 (row,half) slots of C/D
  float red[16];
  #pragma unroll
  for (int r = 0; r < 16; ++r) red[r] = 0.f;

  for (int c = 0; c < 8; ++c) {
    // stage chunk c: 64 KB linear, 16 x 16B glds per thread
    {
      const char* src = (const char*)Wfrag + (size_t)c * 65536 + tid * 16;
      unsigned char* dst = WsB + tid * 16;
      #pragma unroll
      for (int i = 0; i < 16; ++i)
        __builtin_amdgcn_global_load_lds((const unsigned int*)(src + i * 4096),
                                         (unsigned int*)(dst + i * 4096), 16, 0, 0);
    }
    // v for this chunk's two 32-g groups (L1-hot; drained by same vmcnt(0))
    float vv0 = v[c * 64 + l31];
    float vv1 = v[c * 64 + 32 + l31];

    asm volatile("s_waitcnt vmcnt(0)" ::: "memory");
    __builtin_amdgcn_s_barrier();
    __builtin_amdgcn_sched_barrier(0);

    // 4 independent chains: [j][kt-parity], each 16 deep
    f32x16 acc00 = {0}, acc01 = {0}, acc10 = {0}, acc11 = {0};

    const unsigned char* bb = WsB + lane * 16;
    __builtin_amdgcn_s_setprio(1);
    #pragma unroll
    for (int kt = 0; kt < 32; kt += 2) {
      short8 b0a = *reinterpret_cast<const short8*>(bb + (kt)     * 1024);
      short8 b0b = *reinterpret_cast<const short8*>(bb + (kt + 1) * 1024);
      short8 b1a = *reinterpret_cast<const short8*>(bb + 32768 + (kt)     * 1024);
      short8 b1b = *reinterpret_cast<const short8*>(bb + 32768 + (kt + 1) * 1024);
      acc00 = __builtin_amdgcn_mfma_f32_32x32x16_bf16(afrag[kt],     b0a, acc00, 0, 0, 0);
      acc10 = __builtin_amdgcn_mfma_f32_32x32x16_bf16(afrag[kt],     b1a, acc10, 0, 0, 0);
      acc01 = __builtin_amdgcn_mfma_f32_32x32x16_bf16(afrag[kt + 1], b0b, acc01, 0, 0, 0);
      acc11 = __builtin_amdgcn_mfma_f32_32x32x16_bf16(afrag[kt + 1], b1b, acc11, 0, 0, 0);
    }
    __builtin_amdgcn_s_setprio(0);

    // chunk epilogue: e = acc[j][0]+acc[j][1]; red[r] += vv_j * tanh(e)
    #pragma unroll
    for (int r = 0; r < 16; ++r) {
      red[r] = fmaf(vv0, fast_tanh(acc00[r] + acc01[r]), red[r]);
      red[r] = fmaf(vv1, fast_tanh(acc10[r] + acc11[r]), red[r]);
    }

    __builtin_amdgcn_s_barrier();   // all waves done reading before next stage
  }

  // reduce over the 32 g-columns (lanes within each 32-lane half)
  #pragma unroll
  for (int r = 0; r < 16; ++r) {
    #pragma unroll
    for (int d = 1; d < 32; d <<= 1)
      red[r] += __shfl_xor(red[r], d);
  }
  // lane l31==0 of each half writes its 16 rows: row = (r&3)+8*(r>>2)+4*half
  if (l31 == 0) {
    #pragma unroll
    for (int r = 0; r < 16; ++r) {
      int row = (r & 3) + 8 * (r >> 2) + 4 * half;
      sLDS[wave * 32 + row] = red[r];
    }
  }
  __syncthreads();

  // ---- block-local softmax stats over the 128 rows ----
  if (tid < 128) {
    float s = sLDS[tid];
    float m = s;
    #pragma unroll
    for (int d = 1; d < 64; d <<= 1) m = fmaxf(m, __shfl_xor(m, d));
    if ((tid & 63) == 0) mred[tid >> 6] = m;
  }
  __syncthreads();
  const float m_loc = fmaxf(mred[0], mred[1]);
  if (tid < 128) {
    float p = __expf(sLDS[tid] - m_loc);
    pLDS[tid] = p;
    #pragma unroll
    for (int d = 1; d < 64; d <<= 1) p += __shfl_xor(p, d);
    if ((tid & 63) == 0) dred[tid >> 6] = p;
  }
  __syncthreads();

  // ---- partial numerator: thread owns h = 2*tid..+1; X tile L2/L3-assisted ----
  {
    float ax = 0.f, ay = 0.f;
    const float2* xb = reinterpret_cast<const float2*>(X + rowbase * H_SZ) + tid;
    #pragma unroll 8
    for (int t = 0; t < 128; ++t) {
      float p = pLDS[t];
      float2 xv = xb[(size_t)t * (H_SZ / 2)];
      ax = fmaf(p, xv.x, ax);
      ay = fmaf(p, xv.y, ay);
    }
    float2 r; r.x = ax; r.y = ay;
    reinterpret_cast<float2*>(num + (size_t)blockIdx.x * H_SZ)[tid] = r;
  }
  if (tid == 0) {
    float2 r; r.x = m_loc; r.y = dred[0] + dred[1];
    md[blockIdx.x] = r;
  }
}

// ---- combine 32 block-partials per batch with global-max rescale ----
__global__ __launch_bounds__(512) void combine_kernel(
    const float* __restrict__ num, const float2* __restrict__ md,
    float* __restrict__ out) {
  const int b = blockIdx.x;   // 32
  const int h = threadIdx.x;  // 512
  float M = -1e30f;
  #pragma unroll
  for (int c = 0; c < 32; ++c) M = fmaxf(M, md[b * 32 + c].x);
  float den = 0.f, acc = 0.f;
  #pragma unroll 4
  for (int c = 0; c < 32; ++c) {
    float2 m2 = md[b * 32 + c];
    float w = __expf(m2.x - M);
    den += w * m2.y;
    acc = fmaf(w, num[(size_t)(b * 32 + c) * H_SZ + h], acc);
  }
  out[b * H_SZ + h] = acc / den;
}

extern "C" void kernel_launch(void* const* d_in, const int* in_sizes, int n_in,
                              void* d_out, int out_size, void* d_ws, size_t ws_size,
                              hipStream_t stream) {
  const float* X = (const float*)d_in[0];   // (32,4096,512)
  const float* W = (const float*)d_in[1];   // (512,512)
  const float* v = (const float*)d_in[2];   // (512,)
  float* out = (float*)d_out;               // (32,512) fp32
  unsigned char* ws = (unsigned char*)d_ws;

  uint4* Wfrag = (uint4*)(ws);                               // 512 KB
  float* num   = (float*)(ws + (512u << 10));                // 2 MB
  float2* md   = (float2*)(ws + (512u << 10) + (2u << 20));  // 8 KB

  prep_w_kernel<<<128, 256, 0, stream>>>(W, Wfrag);
  score_fused_kernel<<<NROWS / 128, 256, 0, stream>>>(X, Wfrag, v, num, md);
  combine_kernel<<<B_SZ, 512, 0, stream>>>(num, md, out);
}

// Round 15
// 133.888 us; speedup vs baseline: 1.0536x; 1.0536x over previous
//
#include <hip/hip_runtime.h>
#include <hip/hip_bf16.h>

typedef __attribute__((ext_vector_type(8))) short short8;
typedef __attribute__((ext_vector_type(4))) float f32x4;

#define B_SZ 32
#define T_SZ 4096
#define H_SZ 512
#define NROWS (B_SZ * T_SZ)   // 131072

// packed fp32x2 -> bf16x2 (RNE)
static __device__ __forceinline__ unsigned int pack2(float a, float b) {
  unsigned int r;
  asm("v_cvt_pk_bf16_f32 %0, %1, %2" : "=v"(r) : "v"(a), "v"(b));
  return r;
}
// branch-free tanh, exact saturation: 1 - 2/(e^{2x}+1)
static __device__ __forceinline__ float fast_tanh(float x) {
  float e = __expf(2.0f * x);
  return 1.0f - 2.0f / (e + 1.0f);
}

// ---- W fp32 (512x512) -> bf16 fragments, 32g-CHUNK-MAJOR, full-K ----
// uint4 s = c*2048 + j*1024 + kt*64 + kslot*16 + frow   (c = 0..15, j = 0..1)
// holds W[g = c*32 + j*16 + frow][kt*32 + kslot*8 .. +8]
// one chunk c = 32 g x 512 k = 2048 uint4 = 32 KB contiguous, fragment-linear.
__global__ __launch_bounds__(256) void prep_w_kernel(
    const float* __restrict__ W, uint4* __restrict__ Wfrag) {
  int s = blockIdx.x * 256 + threadIdx.x;   // 0..32767
  int frow  = s & 15;
  int kslot = (s >> 4) & 3;
  int kt    = (s >> 6) & 15;
  int j     = (s >> 10) & 1;
  int c     = s >> 11;
  int g  = c * 32 + j * 16 + frow;
  int k0 = kt * 32 + kslot * 8;
  const float4* Wf4 = reinterpret_cast<const float4*>(W);
  float4 lo = Wf4[g * 128 + (k0 >> 2)];
  float4 hi = Wf4[g * 128 + (k0 >> 2) + 1];
  uint4 u;
  u.x = pack2(lo.x, lo.y); u.y = pack2(lo.z, lo.w);
  u.z = pack2(hi.x, hi.y); u.w = pack2(hi.z, hi.w);
  Wfrag[s] = u;
}

// ---- fused: scores + block softmax + partial numerator ----
// 256 thr = 4 waves, wave owns 32 rows (A full-K in regs, 128 VGPR).
// W: 16 chunks of 32 g x 512 k, DOUBLE-buffered 2x32 KB. Per chunk:
// compute (32 ds_read_b128 + 64 MFMA per wave) -> vmcnt(0) [pre-drained:
// stage(ch+1) flew under the compute] -> barrier -> issue stage(ch+2).
// Stage transfer never serializes against the MFMA pipe.
__global__ __launch_bounds__(256, 2) void score_fused_kernel(
    const float* __restrict__ X, const uint4* __restrict__ Wfrag,
    const float* __restrict__ v,
    float* __restrict__ num, float2* __restrict__ md) {
  __shared__ unsigned char WsB[2][32768];  // [j(2)][kt(16)][lane(64)][16B] each
  __shared__ float vLDS[512];
  __shared__ float sLDS[128];
  __shared__ float pLDS[128];
  __shared__ float mred[2], dred[2];

  const int tid   = threadIdx.x;
  const int lane  = tid & 63;
  const int wave  = tid >> 6;
  const int frow  = lane & 15;
  const int kslot = lane >> 4;
  const size_t rowbase = (size_t)blockIdx.x * 128;

  // stage chunk c (32 KB): 8 x 16B linear glds per thread
  #define STAGE(c, buf)                                                         \
    {                                                                           \
      const char* src = (const char*)Wfrag + (size_t)(c) * 32768 + tid * 16;    \
      unsigned char* dst = &WsB[buf][tid * 16];                                 \
      _Pragma("unroll")                                                         \
      for (int i = 0; i < 8; ++i)                                               \
        __builtin_amdgcn_global_load_lds((const unsigned int*)(src + i * 4096), \
                                         (unsigned int*)(dst + i * 4096), 16, 0, 0); \
    }

  // prologue: chunks 0,1 in flight BEFORE the A-load; they land under A-convert
  STAGE(0, 0);
  STAGE(1, 1);
  reinterpret_cast<float2*>(vLDS)[tid] = reinterpret_cast<const float2*>(v)[tid];

  // A fragments, 2 rowsets: X[row][kt*32 + kslot*8 .. +8], bf16-packed (128 VGPR)
  short8 afrag0[16], afrag1[16];
  {
    const float4* xr0 = reinterpret_cast<const float4*>(X + (rowbase + wave * 32 + frow) * H_SZ);
    const float4* xr1 = reinterpret_cast<const float4*>(X + (rowbase + wave * 32 + 16 + frow) * H_SZ);
    #pragma unroll
    for (int kt = 0; kt < 16; ++kt) {
      float4 lo0 = xr0[kt * 8 + kslot * 2];
      float4 hi0 = xr0[kt * 8 + kslot * 2 + 1];
      union { uint4 u; short8 s; } c0;
      c0.u.x = pack2(lo0.x, lo0.y); c0.u.y = pack2(lo0.z, lo0.w);
      c0.u.z = pack2(hi0.x, hi0.y); c0.u.w = pack2(hi0.z, hi0.w);
      afrag0[kt] = c0.s;
      float4 lo1 = xr1[kt * 8 + kslot * 2];
      float4 hi1 = xr1[kt * 8 + kslot * 2 + 1];
      union { uint4 u; short8 s; } c1;
      c1.u.x = pack2(lo1.x, lo1.y); c1.u.y = pack2(lo1.z, lo1.w);
      c1.u.z = pack2(hi1.x, hi1.y); c1.u.w = pack2(hi1.z, hi1.w);
      afrag1[kt] = c1.s;
    }
  }
  // A-converts already drained stage 0/1 (older vmem); sync LDS + waves
  asm volatile("s_waitcnt vmcnt(0) lgkmcnt(0)" ::: "memory");
  __builtin_amdgcn_s_barrier();
  __builtin_amdgcn_sched_barrier(0);

  float red0[4] = {0.f, 0.f, 0.f, 0.f};
  float red1[4] = {0.f, 0.f, 0.f, 0.f};

  for (int ch = 0; ch < 16; ++ch) {
    const int buf = ch & 1;
    float vv0 = vLDS[ch * 32 + frow];
    float vv1 = vLDS[ch * 32 + 16 + frow];

    f32x4 acc[2][2];   // [rowset][j]
    #pragma unroll
    for (int a = 0; a < 2; ++a)
      #pragma unroll
      for (int j = 0; j < 2; ++j)
        acc[a][j] = (f32x4){0.f, 0.f, 0.f, 0.f};

    const unsigned char* bb = &WsB[buf][lane * 16];
    __builtin_amdgcn_s_setprio(1);
    #pragma unroll
    for (int kt = 0; kt < 16; ++kt) {
      short8 b0 = *reinterpret_cast<const short8*>(bb + kt * 1024);          // j=0
      short8 b1 = *reinterpret_cast<const short8*>(bb + 16384 + kt * 1024);  // j=1
      acc[0][0] = __builtin_amdgcn_mfma_f32_16x16x32_bf16(afrag0[kt], b0, acc[0][0], 0, 0, 0);
      acc[1][0] = __builtin_amdgcn_mfma_f32_16x16x32_bf16(afrag1[kt], b0, acc[1][0], 0, 0, 0);
      acc[0][1] = __builtin_amdgcn_mfma_f32_16x16x32_bf16(afrag0[kt], b1, acc[0][1], 0, 0, 0);
      acc[1][1] = __builtin_amdgcn_mfma_f32_16x16x32_bf16(afrag1[kt], b1, acc[1][1], 0, 0, 0);
    }
    __builtin_amdgcn_s_setprio(0);

    // chunk epilogue: D[m][n] n=frow within j-group, m=kslot*4+r
    #pragma unroll
    for (int r = 0; r < 4; ++r) {
      red0[r] = fmaf(vv0, fast_tanh(acc[0][0][r]), red0[r]);
      red0[r] = fmaf(vv1, fast_tanh(acc[0][1][r]), red0[r]);
      red1[r] = fmaf(vv0, fast_tanh(acc[1][0][r]), red1[r]);
      red1[r] = fmaf(vv1, fast_tanh(acc[1][1][r]), red1[r]);
    }

    // stage(ch+1) had the whole compute to land -> vmcnt(0) is ~free.
    // barrier: all waves done reading buf, then reuse it for chunk ch+2.
    asm volatile("s_waitcnt vmcnt(0)" ::: "memory");
    __builtin_amdgcn_s_barrier();
    __builtin_amdgcn_sched_barrier(0);
    if (ch + 2 < 16) STAGE(ch + 2, buf);
  }
  #undef STAGE

  // reduce over the 16 g-lanes (frow) within each kslot group
  #pragma unroll
  for (int r = 0; r < 4; ++r) {
    #pragma unroll
    for (int d = 1; d < 16; d <<= 1) {
      red0[r] += __shfl_xor(red0[r], d);
      red1[r] += __shfl_xor(red1[r], d);
    }
  }
  if (frow == 0) {
    float* sp = sLDS + wave * 32 + kslot * 4;
    sp[0]  = red0[0]; sp[1]  = red0[1]; sp[2]  = red0[2]; sp[3]  = red0[3];
    sp[16] = red1[0]; sp[17] = red1[1]; sp[18] = red1[2]; sp[19] = red1[3];
  }
  __syncthreads();

  // ---- block-local softmax stats over the 128 rows ----
  if (tid < 128) {
    float s = sLDS[tid];
    float m = s;
    #pragma unroll
    for (int d = 1; d < 64; d <<= 1) m = fmaxf(m, __shfl_xor(m, d));
    if ((tid & 63) == 0) mred[tid >> 6] = m;
  }
  __syncthreads();
  const float m_loc = fmaxf(mred[0], mred[1]);
  if (tid < 128) {
    float p = __expf(sLDS[tid] - m_loc);
    pLDS[tid] = p;
    #pragma unroll
    for (int d = 1; d < 64; d <<= 1) p += __shfl_xor(p, d);
    if ((tid & 63) == 0) dred[tid >> 6] = p;
  }
  __syncthreads();

  // ---- partial numerator: thread owns h = 2*tid..+1; X tile L2/L3-hot ----
  {
    float ax = 0.f, ay = 0.f;
    const float2* xb = reinterpret_cast<const float2*>(X + rowbase * H_SZ) + tid;
    #pragma unroll 8
    for (int t = 0; t < 128; ++t) {
      float p = pLDS[t];
      float2 xv = xb[(size_t)t * (H_SZ / 2)];
      ax = fmaf(p, xv.x, ax);
      ay = fmaf(p, xv.y, ay);
    }
    float2 r; r.x = ax; r.y = ay;
    reinterpret_cast<float2*>(num + (size_t)blockIdx.x * H_SZ)[tid] = r;
  }
  if (tid == 0) {
    float2 r; r.x = m_loc; r.y = dred[0] + dred[1];
    md[blockIdx.x] = r;
  }
}

// ---- combine 32 block-partials per batch with global-max rescale ----
__global__ __launch_bounds__(512) void combine_kernel(
    const float* __restrict__ num, const float2* __restrict__ md,
    float* __restrict__ out) {
  const int b = blockIdx.x;   // 32
  const int h = threadIdx.x;  // 512
  float M = -1e30f;
  #pragma unroll
  for (int c = 0; c < 32; ++c) M = fmaxf(M, md[b * 32 + c].x);
  float den = 0.f, acc = 0.f;
  #pragma unroll 4
  for (int c = 0; c < 32; ++c) {
    float2 m2 = md[b * 32 + c];
    float w = __expf(m2.x - M);
    den += w * m2.y;
    acc = fmaf(w, num[(size_t)(b * 32 + c) * H_SZ + h], acc);
  }
  out[b * H_SZ + h] = acc / den;
}

extern "C" void kernel_launch(void* const* d_in, const int* in_sizes, int n_in,
                              void* d_out, int out_size, void* d_ws, size_t ws_size,
                              hipStream_t stream) {
  const float* X = (const float*)d_in[0];   // (32,4096,512)
  const float* W = (const float*)d_in[1];   // (512,512)
  const float* v = (const float*)d_in[2];   // (512,)
  float* out = (float*)d_out;               // (32,512) fp32
  unsigned char* ws = (unsigned char*)d_ws;

  uint4* Wfrag = (uint4*)(ws);                               // 512 KB
  float* num   = (float*)(ws + (512u << 10));                // 2 MB
  float2* md   = (float2*)(ws + (512u << 10) + (2u << 20));  // 8 KB

  prep_w_kernel<<<128, 256, 0, stream>>>(W, Wfrag);
  score_fused_kernel<<<NROWS / 128, 256, 0, stream>>>(X, Wfrag, v, num, md);
  combine_kernel<<<B_SZ, 512, 0, stream>>>(num, md, out);
}